// Round 1
// baseline (668.788 us; speedup 1.0000x reference)
//
#include <hip/hip_runtime.h>

// PCLSTM: B=512, C=128, H=128, T=512. Single fused persistent kernel.
// 64 workgroups x 1024 threads; each wg owns MB=8 batch rows for all T steps.
// Weights held in registers as MFMA B-fragments (bf16); h/c state: h in LDS
// (bf16) + c in registers (fp32). x staged in LDS in t-chunks of 32.

#define BB   512
#define CC   128
#define HH   128
#define TT   512
#define MB   8      // batch rows per workgroup
#define TCH  32     // t-chunk staged in LDS
#define LDP  136    // padded LDS row length (bf16 elems) to break bank conflicts
#define ZLP  (4*HH + 4)

typedef __attribute__((ext_vector_type(8))) short short8;
typedef __attribute__((ext_vector_type(4))) float f32x4;

__device__ inline unsigned short f2bf(float f) {
    unsigned u = __builtin_bit_cast(unsigned, f);
    u = u + 0x7FFFu + ((u >> 16) & 1u);   // round-to-nearest-even
    return (unsigned short)(u >> 16);
}

__device__ inline float fsigmoid(float x) {
    float e = __builtin_amdgcn_exp2f(-1.4426950408889634f * x);
    return __builtin_amdgcn_rcpf(1.0f + e);
}
__device__ inline float ftanh(float x) {
    float e = __builtin_amdgcn_exp2f(2.8853900817779268f * x);  // 2^(2x*log2e)
    return 1.0f - 2.0f * __builtin_amdgcn_rcpf(e + 1.0f);
}

__global__ __launch_bounds__(1024) void pclstm_kernel(
    const float* __restrict__ x,
    const float* __restrict__ Wf, const float* __restrict__ bf_,
    const float* __restrict__ Wi, const float* __restrict__ bi_,
    const float* __restrict__ Wu, const float* __restrict__ bu_,
    const float* __restrict__ Wo, const float* __restrict__ bo_,
    float* __restrict__ out)
{
    __shared__ unsigned short xs[TCH][MB][LDP];   // staged x, bf16: [t][b][c]
    __shared__ unsigned short hs[MB][LDP];        // h state, bf16: [b][n]
    __shared__ float zl[MB][ZLP];                 // gate preactivations

    const int tid  = threadIdx.x;
    const int lane = tid & 63;
    const int wid  = tid >> 6;          // wave 0..15, owns cols [32w, 32w+32)
    const int bg0  = blockIdx.x * MB;   // global batch base

    // ---- one-time: load weight B-fragments into registers (bf16) ----
    // big-K s = [x(128), h(128)]; W rows 0..255 map directly. Column j in
    // [0,512): gate g=j>>7 (f,i,u,o), unit n=j&127.
    const float* Wg[4] = {Wf, Wi, Wu, Wo};
    const float* Bg[4] = {bf_, bi_, bu_, bo_};
    short8 wfrag[2][8];
    float bias[2];
    const int koff = (lane >> 4) << 3;  // 0,8,16,24 : k-offset within k-tile
    #pragma unroll
    for (int nt = 0; nt < 2; ++nt) {
        int j = wid * 32 + nt * 16 + (lane & 15);
        const float* Wp = Wg[j >> 7];
        int n = j & 127;
        bias[nt] = Bg[j >> 7][n];
        #pragma unroll
        for (int kt = 0; kt < 8; ++kt) {
            short8 v;
            #pragma unroll
            for (int i = 0; i < 8; ++i) {
                int krow = kt * 32 + koff + i;        // 0..255
                v[i] = (short)f2bf(Wp[krow * HH + n]);
            }
            wfrag[nt][kt] = v;
        }
    }

    // zero h state
    for (int idx = tid; idx < MB * LDP; idx += 1024)
        ((unsigned short*)hs)[idx] = 0;

    // elementwise identity: one (b,n) unit per thread
    const int eb = tid >> 7;      // 0..7
    const int en = tid & 127;     // 0..127
    float c = 0.0f;
    float* outH = out;                              // (B,H,T)
    float* outC = out + (size_t)BB * HH * TT;       // (B,H)

    const int arow = lane & 7;    // A-frag row (rows 8..15 mirror 0..7, discarded)

    __syncthreads();

    for (int t = 0; t < TT; ++t) {
        if ((t & (TCH - 1)) == 0) {
            // stage x[bg0..bg0+8) x [0,128) x [t, t+TCH) -> bf16 LDS
            const float* xp = x + ((size_t)(bg0 + eb) * CC + en) * TT + t;
            #pragma unroll
            for (int q = 0; q < TCH / 4; ++q) {
                float4 v = reinterpret_cast<const float4*>(xp)[q];
                xs[q * 4 + 0][eb][en] = f2bf(v.x);
                xs[q * 4 + 1][eb][en] = f2bf(v.y);
                xs[q * 4 + 2][eb][en] = f2bf(v.z);
                xs[q * 4 + 3][eb][en] = f2bf(v.w);
            }
            __syncthreads();
        }
        const int ts = t & (TCH - 1);

        // ---- MFMA phase: z(8x512) = [x_t,h](8x256) @ W(256x512) + b ----
        f32x4 acc0 = {bias[0], bias[0], bias[0], bias[0]};
        f32x4 acc1 = {bias[1], bias[1], bias[1], bias[1]};
        #pragma unroll
        for (int kt = 0; kt < 8; ++kt) {
            short8 a;
            if (kt < 4)
                a = *reinterpret_cast<const short8*>(&xs[ts][arow][kt * 32 + koff]);
            else
                a = *reinterpret_cast<const short8*>(&hs[arow][(kt - 4) * 32 + koff]);
            acc0 = __builtin_amdgcn_mfma_f32_16x16x32_bf16(a, wfrag[0][kt], acc0, 0, 0, 0);
            acc1 = __builtin_amdgcn_mfma_f32_16x16x32_bf16(a, wfrag[1][kt], acc1, 0, 0, 0);
        }
        // D layout: col = lane&15, row = (lane>>4)*4 + r. Rows >=8 are garbage.
        if (lane < 32) {
            int r0 = (lane >> 4) * 4;
            int cb = wid * 32 + (lane & 15);
            #pragma unroll
            for (int r = 0; r < 4; ++r) {
                zl[r0 + r][cb]      = acc0[r];
                zl[r0 + r][cb + 16] = acc1[r];
            }
        }
        __syncthreads();

        // ---- elementwise phase ----
        float zf = zl[eb][en];
        float zi = zl[eb][HH + en];
        float zu = zl[eb][2 * HH + en];
        float zo = zl[eb][3 * HH + en];
        float fg = fsigmoid(zf);
        float ig = fsigmoid(zi);
        float gg = ftanh(zu);
        float og = fsigmoid(zo);
        c = c * fg + ig * gg;
        float h = og * ftanh(c);
        outH[((size_t)(bg0 + eb) * HH + en) * TT + t] = h;
        hs[eb][en] = f2bf(h);
        __syncthreads();
    }
    outC[(size_t)(bg0 + eb) * HH + en] = c;
}

extern "C" void kernel_launch(void* const* d_in, const int* in_sizes, int n_in,
                              void* d_out, int out_size, void* d_ws, size_t ws_size,
                              hipStream_t stream) {
    const float* x  = (const float*)d_in[0];
    const float* Wf = (const float*)d_in[1];
    const float* bf = (const float*)d_in[2];
    const float* Wi = (const float*)d_in[3];
    const float* bi = (const float*)d_in[4];
    const float* Wu = (const float*)d_in[5];
    const float* bu = (const float*)d_in[6];
    const float* Wo = (const float*)d_in[7];
    const float* bo = (const float*)d_in[8];
    float* out = (float*)d_out;

    dim3 grid(BB / MB);   // 64 workgroups
    dim3 block(1024);
    pclstm_kernel<<<grid, block, 0, stream>>>(x, Wf, bf, Wi, bi, Wu, bu, Wo, bo, out);
}

// Round 2
// 437.060 us; speedup vs baseline: 1.5302x; 1.5302x over previous
//
#include <hip/hip_runtime.h>

// PCLSTM: B=512, C=128, H=128, T=512. Single fused persistent kernel.
// 256 workgroups x 512 threads (8 waves); each wg owns MB=2 batch rows for
// all T steps. Wave w owns ALL FOUR gates of hidden units n in [16w,16w+16)
// so gate preactivations stay in registers (no z roundtrip via LDS).
// Weights in registers as MFMA B-fragments (128 VGPR). h double-buffered in
// LDS (bf16) -> one barrier per step. h output buffered in LDS for TCH=16
// steps, then written to global as coalesced float4 lines.

#define BB   512
#define CC   128
#define HH   128
#define TT   512
#define MB   2      // batch rows per workgroup
#define TCH  16     // t-chunk (x staging + h write-back granularity)
#define XP   136    // xs/hs padded row length (bf16) - 16B aligned rows
#define OP   20     // hbuf padded inner length (fp32) - 16B aligned, bank-spread

typedef __attribute__((ext_vector_type(8))) short short8;
typedef __attribute__((ext_vector_type(4))) float f32x4;

__device__ inline unsigned short f2bf(float f) {
    unsigned u = __builtin_bit_cast(unsigned, f);
    u = u + 0x7FFFu + ((u >> 16) & 1u);   // round-to-nearest-even
    return (unsigned short)(u >> 16);
}

__device__ inline float fsigmoid(float x) {
    float e = __builtin_amdgcn_exp2f(-1.4426950408889634f * x);
    return __builtin_amdgcn_rcpf(1.0f + e);
}
__device__ inline float ftanh(float x) {
    float e = __builtin_amdgcn_exp2f(2.8853900817779268f * x);  // 2^(2x*log2e)
    return 1.0f - 2.0f * __builtin_amdgcn_rcpf(e + 1.0f);
}

__global__ __launch_bounds__(512, 2) void pclstm_kernel(
    const float* __restrict__ x,
    const float* __restrict__ Wf, const float* __restrict__ bf_,
    const float* __restrict__ Wi, const float* __restrict__ bi_,
    const float* __restrict__ Wu, const float* __restrict__ bu_,
    const float* __restrict__ Wo, const float* __restrict__ bo_,
    float* __restrict__ out)
{
    __shared__ unsigned short xs[TCH][MB][XP];  // staged x (bf16): [tt][b][c]
    __shared__ unsigned short hs[2][MB][XP];    // h state (bf16), double-buffered
    __shared__ float hbuf[MB][HH][OP];          // fp32 h accumulation for chunk

    const int tid  = threadIdx.x;
    const int lane = tid & 63;
    const int wid  = tid >> 6;            // 0..7
    const int bg0  = blockIdx.x * MB;
    const int l15  = lane & 15;
    const int koff = (lane >> 4) << 3;    // 0,8,16,24
    const int arow = lane & (MB - 1);     // A rows beyond MB duplicate row 0/1
    const int n16  = wid * 16 + l15;      // this lane's hidden unit (B-frag col)

    // ---- one-time: weight B-fragments into registers (bf16) ----
    const float* Wg[4] = {Wf, Wi, Wu, Wo};
    const float* Bg[4] = {bf_, bi_, bu_, bo_};
    short8 wfrag[4][8];
    float bias[4];
    #pragma unroll
    for (int g = 0; g < 4; ++g) {
        const float* Wp = Wg[g];
        bias[g] = Bg[g][n16];
        #pragma unroll
        for (int kt = 0; kt < 8; ++kt) {
            short8 v;
            #pragma unroll
            for (int i = 0; i < 8; ++i)
                v[i] = (short)f2bf(Wp[(kt * 32 + koff + i) * HH + n16]);
            wfrag[g][kt] = v;
        }
    }

    // zero h state (both buffers)
    for (int idx = tid; idx < 2 * MB * XP; idx += 512)
        ((unsigned short*)hs)[idx] = 0;

    float cst0 = 0.0f, cst1 = 0.0f;
    float* outH = out;
    float* outC = out + (size_t)BB * HH * TT;
    int p = 0;

    __syncthreads();

    for (int tc = 0; tc < TT / TCH; ++tc) {
        const int t0 = tc * TCH;

        // ---- stage x chunk: (2 batch rows) x 128 ch x 16 t -> bf16 LDS ----
        if (tid < MB * CC) {
            const int b = tid >> 7, cc = tid & 127;
            const float* xp = x + ((size_t)(bg0 + b) * CC + cc) * TT + t0;
            #pragma unroll
            for (int q = 0; q < TCH / 4; ++q) {
                float4 v = reinterpret_cast<const float4*>(xp)[q];
                xs[q * 4 + 0][b][cc] = f2bf(v.x);
                xs[q * 4 + 1][b][cc] = f2bf(v.y);
                xs[q * 4 + 2][b][cc] = f2bf(v.z);
                xs[q * 4 + 3][b][cc] = f2bf(v.w);
            }
        }
        // ---- write previous chunk's h to global, coalesced ----
        if (tc > 0) {
            const int t0p = t0 - TCH;
            #pragma unroll
            for (int k = 0; k < 2; ++k) {
                int v = tid + k * 512;          // 0..1023
                int q = v & 3, unit = v >> 2;   // unit 0..255
                int b = unit >> 7, n = unit & 127;
                float4 vv = *reinterpret_cast<const float4*>(&hbuf[b][n][q * 4]);
                *reinterpret_cast<float4*>(
                    outH + ((size_t)(bg0 + b) * HH + n) * TT + t0p + q * 4) = vv;
            }
        }
        __syncthreads();

        #pragma unroll 2
        for (int tt = 0; tt < TCH; ++tt) {
            // ---- MFMA: z(2x512) = [x_t,h](2x256) @ W(256x512) + b ----
            f32x4 acc[4];
            #pragma unroll
            for (int g = 0; g < 4; ++g)
                acc[g] = (f32x4){bias[g], bias[g], bias[g], bias[g]};
            #pragma unroll
            for (int kt = 0; kt < 8; ++kt) {
                short8 a;
                if (kt < 4)
                    a = *reinterpret_cast<const short8*>(&xs[tt][arow][kt * 32 + koff]);
                else
                    a = *reinterpret_cast<const short8*>(&hs[p][arow][(kt - 4) * 32 + koff]);
                #pragma unroll
                for (int g = 0; g < 4; ++g)
                    acc[g] = __builtin_amdgcn_mfma_f32_16x16x32_bf16(a, wfrag[g][kt], acc[g], 0, 0, 0);
            }
            // D layout: col = lane&15, row = (lane>>4)*4 + reg.
            // Valid batch rows 0,1 live in lanes 0-15, regs 0,1.
            if (lane < 16) {
                float fg, ig, gg, og, h0, h1;
                fg = fsigmoid(acc[0][0]); ig = fsigmoid(acc[1][0]);
                gg = ftanh(acc[2][0]);    og = fsigmoid(acc[3][0]);
                cst0 = cst0 * fg + ig * gg;
                h0 = og * ftanh(cst0);
                fg = fsigmoid(acc[0][1]); ig = fsigmoid(acc[1][1]);
                gg = ftanh(acc[2][1]);    og = fsigmoid(acc[3][1]);
                cst1 = cst1 * fg + ig * gg;
                h1 = og * ftanh(cst1);
                hs[p ^ 1][0][n16] = f2bf(h0);
                hs[p ^ 1][1][n16] = f2bf(h1);
                hbuf[0][n16][tt] = h0;
                hbuf[1][n16][tt] = h1;
            }
            __syncthreads();
            p ^= 1;
        }
    }

    // final chunk h write
    {
        const int t0p = TT - TCH;
        #pragma unroll
        for (int k = 0; k < 2; ++k) {
            int v = tid + k * 512;
            int q = v & 3, unit = v >> 2;
            int b = unit >> 7, n = unit & 127;
            float4 vv = *reinterpret_cast<const float4*>(&hbuf[b][n][q * 4]);
            *reinterpret_cast<float4*>(
                outH + ((size_t)(bg0 + b) * HH + n) * TT + t0p + q * 4) = vv;
        }
    }
    if (lane < 16) {
        outC[(size_t)(bg0 + 0) * HH + n16] = cst0;
        outC[(size_t)(bg0 + 1) * HH + n16] = cst1;
    }
}

extern "C" void kernel_launch(void* const* d_in, const int* in_sizes, int n_in,
                              void* d_out, int out_size, void* d_ws, size_t ws_size,
                              hipStream_t stream) {
    const float* x  = (const float*)d_in[0];
    const float* Wf = (const float*)d_in[1];
    const float* bf = (const float*)d_in[2];
    const float* Wi = (const float*)d_in[3];
    const float* bi = (const float*)d_in[4];
    const float* Wu = (const float*)d_in[5];
    const float* bu = (const float*)d_in[6];
    const float* Wo = (const float*)d_in[7];
    const float* bo = (const float*)d_in[8];
    float* out = (float*)d_out;

    dim3 grid(BB / MB);   // 256 workgroups, one per CU
    dim3 block(512);      // 8 waves
    pclstm_kernel<<<grid, block, 0, stream>>>(x, Wf, bf, Wi, bi, Wu, bu, Wo, bo, out);
}